// Round 4
// baseline (290.389 us; speedup 1.0000x reference)
//
#include <hip/hip_runtime.h>
#include <hip/hip_bf16.h>

// Inputs fp32 (confirmed round 2). Internal pipeline bf16 MFMA.
// Factored exp trick: w(i,j) = e>0 ? exp(e) : exp(0.2e), e = src_i + dst_j
//   = (B_j > T_i) ? A_i*B_j : C_i*D_j, all exps precomputed per row/col.

typedef unsigned short ushort_t;
typedef __attribute__((ext_vector_type(8))) short bf16x8;
typedef __attribute__((ext_vector_type(4))) float f32x4;

#define LOG2E 1.4426950408889634f

__device__ __forceinline__ ushort_t f2bf(float x) {
    unsigned u = __builtin_bit_cast(unsigned, x);
    u += 0x7FFFu + ((u >> 16) & 1u);   // RNE
    return (ushort_t)(u >> 16);
}

// ---------------- kernel 1: WT[c][k] = W[k][c], 512x512, fp32 -> bf16 ----------------
__global__ __launch_bounds__(256) void transpose_w(const float* __restrict__ W,
                                                   ushort_t* __restrict__ WT) {
    __shared__ ushort_t t[32][33];
    int bx = blockIdx.x & 15, by = blockIdx.x >> 4;
    int tx = threadIdx.x & 31, ty = threadIdx.x >> 5;
#pragma unroll
    for (int i = 0; i < 32; i += 8)
        t[ty + i][tx] = f2bf(W[(by * 32 + ty + i) * 512 + bx * 32 + tx]);
    __syncthreads();
#pragma unroll
    for (int i = 0; i < 32; i += 8)
        WT[(bx * 32 + ty + i) * 512 + by * 32 + tx] = t[tx][ty + i];
}

// ---------------- kernel 2: streaming GEMM, no LDS tiles, no barriers ----------------
// WhT[c][n] = sum_k WT[c][k] h[n][k]; block = 64c x 64n, wave w -> c-strip w*16.
// Epilogue: fused src/dst projections -> exp arrays A,C,T (rows) and B,D (cols).
__global__ __launch_bounds__(256) void gemm_whT(const ushort_t* __restrict__ WT,
                                                const float* __restrict__ h,
                                                const float* __restrict__ a,
                                                ushort_t* __restrict__ WhT,
                                                float* __restrict__ expA,
                                                float* __restrict__ expC,
                                                float* __restrict__ expT,
                                                float* __restrict__ expB,
                                                float* __restrict__ expD) {
    __shared__ float asrc[64], adst[64];
    __shared__ float sred[2][4][64];
    int tid = threadIdx.x;
    int wave = tid >> 6, lane = tid & 63, quad = lane >> 4, nn = lane & 15;
    int mb = blockIdx.x & 7, nb = blockIdx.x >> 3;
    if (tid < 64) {
        asrc[tid] = a[tid] * LOG2E;
        adst[tid] = a[64 + tid] * LOG2E;
    }
    const ushort_t* Ap = WT + (unsigned)((mb * 64 + wave * 16 + nn) * 512 + quad * 8);
    const float* Hb = h + (unsigned)((nb * 64 + nn) * 512 + quad * 8);
    f32x4 acc[4] = {};
#pragma unroll 4
    for (int kb = 0; kb < 512; kb += 32) {
        bf16x8 af = *(const bf16x8*)(Ap + kb);
#pragma unroll
        for (int nt = 0; nt < 4; nt++) {
            const float* hp = Hb + nt * 16 * 512 + kb;
            float4 f0 = *(const float4*)hp;
            float4 f1 = *(const float4*)(hp + 4);
            bf16x8 bv;
            bv[0] = (short)f2bf(f0.x); bv[1] = (short)f2bf(f0.y);
            bv[2] = (short)f2bf(f0.z); bv[3] = (short)f2bf(f0.w);
            bv[4] = (short)f2bf(f1.x); bv[5] = (short)f2bf(f1.y);
            bv[6] = (short)f2bf(f1.z); bv[7] = (short)f2bf(f1.w);
            acc[nt] = __builtin_amdgcn_mfma_f32_16x16x32_bf16(af, bv, acc[nt], 0, 0, 0);
        }
    }
    __syncthreads();   // asrc/adst visible
    int row0 = mb * 64 + wave * 16 + quad * 4;
    int col0 = nb * 64 + nn;
    int f0i = wave * 16 + quad * 4;
#pragma unroll
    for (int nt = 0; nt < 4; nt++) {
        float s = 0.f, d = 0.f;
#pragma unroll
        for (int rr = 0; rr < 4; rr++) {
            float v = acc[nt][rr];
            WhT[(unsigned)((row0 + rr) * 4096 + col0 + nt * 16)] = f2bf(v);
            s += v * asrc[f0i + rr];
            d += v * adst[f0i + rr];
        }
        s += __shfl_xor(s, 16); s += __shfl_xor(s, 32);
        d += __shfl_xor(d, 16); d += __shfl_xor(d, 32);
        if (quad == 0) { sred[0][wave][nt * 16 + nn] = s; sred[1][wave][nt * 16 + nn] = d; }
    }
    __syncthreads();
    if (tid < 64) {
        float s = sred[0][0][tid] + sred[0][1][tid] + sred[0][2][tid] + sred[0][3][tid];
        unsigned idx = mb * 4096 + nb * 64 + tid;
        expA[idx] = __builtin_amdgcn_exp2f(s);
        expC[idx] = __builtin_amdgcn_exp2f(0.2f * s);
        expT[idx] = __builtin_amdgcn_exp2f(-s);
    } else if (tid < 128) {
        int c = tid - 64;
        float d = sred[1][0][c] + sred[1][1][c] + sred[1][2][c] + sred[1][3][c];
        unsigned idx = mb * 4096 + nb * 64 + c;
        expB[idx] = __builtin_amdgcn_exp2f(d);
        expD[idx] = __builtin_amdgcn_exp2f(0.2f * d);
    }
}

// ---------------- kernel 3: fused masked-softmax attention + P@V + ELU ----------------
// 1024 blocks x 512 thr. Block = 16 i-rows x 2 heads; j-tile 64, dbuf P, 1 barrier/iter.
// hb = bid&3 so co-resident blocks share the V window (L1 reuse).
__global__ __launch_bounds__(512, 8) void gat_attn(const int* __restrict__ adj,
                                                   const ushort_t* __restrict__ WhT,
                                                   const float* __restrict__ expA,
                                                   const float* __restrict__ expC,
                                                   const float* __restrict__ expT,
                                                   const float* __restrict__ expB,
                                                   const float* __restrict__ expD,
                                                   float* __restrict__ out) {
    __shared__ __align__(16) ushort_t Pb[2][2][16][72];   // 9216 B
    __shared__ float denoml[2][16];
    __shared__ __align__(16) float cmb[2][2][64][8];      // 4096 B
    int tid = threadIdx.x;
    int wave = tid >> 6, lane = tid & 63, quad = lane >> 4, nn = lane & 15;
    int hb = blockIdx.x & 3, ib = blockIdx.x >> 2;
    int i0 = ib * 16;
    // gen role: 4 j-entries per thread per iter
    int hh = tid >> 8, tt = tid & 255;
    int pi = tt >> 4, jo = tt & 15;
    int head = hb * 2 + hh;
    float Ai = expA[head * 4096 + i0 + pi];
    float Ci = expC[head * 4096 + i0 + pi];
    float Ti = expT[head * 4096 + i0 + pi];
    unsigned aoff = (unsigned)(i0 + pi) * 4096 + jo * 4;
    unsigned boff = (unsigned)head * 4096 + jo * 4;
    // MFMA role
    int whead = wave & 1, jhalf = (wave >> 1) & 1, nhalf = wave >> 2;
    unsigned voff0 = (unsigned)(hb * 128 + whead * 64 + nhalf * 32 + nn) * 4096
                     + jhalf * 32 + quad * 8;
    unsigned voff1 = voff0 + 16u * 4096u;
    f32x4 acc0 = {}, acc1 = {};
    float dpart = 0.f;
    int4 pa = *(const int4*)(adj + aoff);
#pragma unroll 2
    for (int k = 0; k < 64; k++) {
        int cb = k & 1;
        int4 av = pa;
        if (k < 63) pa = *(const int4*)(adj + aoff + (k + 1) * 64);
        float4 Bv = *(const float4*)(expB + boff + k * 64);
        float4 Dv = *(const float4*)(expD + boff + k * 64);
        unsigned w0, w1, w2, w3;
        {
            float s1, s2, w;
            s1 = Bv.x > Ti ? Bv.x : Dv.x;  s2 = Bv.x > Ti ? Ai : Ci;  w = s1 * s2;
            w0 = __builtin_bit_cast(unsigned, w) & 0xFFFF0000u;  w0 = av.x > 0 ? w0 : 0u;
            s1 = Bv.y > Ti ? Bv.y : Dv.y;  s2 = Bv.y > Ti ? Ai : Ci;  w = s1 * s2;
            w1 = __builtin_bit_cast(unsigned, w) & 0xFFFF0000u;  w1 = av.y > 0 ? w1 : 0u;
            s1 = Bv.z > Ti ? Bv.z : Dv.z;  s2 = Bv.z > Ti ? Ai : Ci;  w = s1 * s2;
            w2 = __builtin_bit_cast(unsigned, w) & 0xFFFF0000u;  w2 = av.z > 0 ? w2 : 0u;
            s1 = Bv.w > Ti ? Bv.w : Dv.w;  s2 = Bv.w > Ti ? Ai : Ci;  w = s1 * s2;
            w3 = __builtin_bit_cast(unsigned, w) & 0xFFFF0000u;  w3 = av.w > 0 ? w3 : 0u;
        }
        dpart += __builtin_bit_cast(float, w0) + __builtin_bit_cast(float, w1)
               + __builtin_bit_cast(float, w2) + __builtin_bit_cast(float, w3);
        unsigned q0 = __builtin_amdgcn_perm(w1, w0, 0x07060302u);
        unsigned q1 = __builtin_amdgcn_perm(w3, w2, 0x07060302u);
        *(uint2*)&Pb[cb][hh][pi][jo * 4] = make_uint2(q0, q1);
        if (k > 0) {
            int pbuf = cb ^ 1;
            bf16x8 af = *(const bf16x8*)&Pb[pbuf][whead][nn][jhalf * 32 + quad * 8];
            bf16x8 b0 = *(const bf16x8*)(WhT + voff0 + (k - 1) * 64);
            bf16x8 b1 = *(const bf16x8*)(WhT + voff1 + (k - 1) * 64);
            acc0 = __builtin_amdgcn_mfma_f32_16x16x32_bf16(af, b0, acc0, 0, 0, 0);
            acc1 = __builtin_amdgcn_mfma_f32_16x16x32_bf16(af, b1, acc1, 0, 0, 0);
        }
        __syncthreads();
    }
    {   // tail: tile 63 (buffer 1)
        bf16x8 af = *(const bf16x8*)&Pb[1][whead][nn][jhalf * 32 + quad * 8];
        bf16x8 b0 = *(const bf16x8*)(WhT + voff0 + 63 * 64);
        bf16x8 b1 = *(const bf16x8*)(WhT + voff1 + 63 * 64);
        acc0 = __builtin_amdgcn_mfma_f32_16x16x32_bf16(af, b0, acc0, 0, 0, 0);
        acc1 = __builtin_amdgcn_mfma_f32_16x16x32_bf16(af, b1, acc1, 0, 0, 0);
    }
    // denominator: reduce over jo = low 4 lane bits
    float dsum = dpart;
    dsum += __shfl_xor(dsum, 1);
    dsum += __shfl_xor(dsum, 2);
    dsum += __shfl_xor(dsum, 4);
    dsum += __shfl_xor(dsum, 8);
    if ((lane & 15) == 0) denoml[hh][pi] = dsum;
    // jhalf=1 waves publish partials
    if (jhalf == 1) {
        *(f32x4*)&cmb[whead][nhalf][lane][0] = acc0;
        *(f32x4*)&cmb[whead][nhalf][lane][4] = acc1;
    }
    __syncthreads();
    if (jhalf == 0) {
        f32x4 o0 = acc0 + *(const f32x4*)&cmb[whead][nhalf][lane][0];
        f32x4 o1 = acc1 + *(const f32x4*)&cmb[whead][nhalf][lane][4];
#pragma unroll
        for (int rr = 0; rr < 4; rr++) {
            int il = quad * 4 + rr;
            float dnm = fmaxf(denoml[whead][il], 1e-30f);
            float v0 = o0[rr] / dnm;
            float v1 = o1[rr] / dnm;
            v0 = v0 > 0.f ? v0 : __expf(v0) - 1.f;
            v1 = v1 > 0.f ? v1 : __expf(v1) - 1.f;
            unsigned oi = (unsigned)(i0 + il) * 512 + hb * 128 + whead * 64
                        + nhalf * 32 + nn;
            out[oi] = v0;
            out[oi + 16] = v1;
        }
    }
}

extern "C" void kernel_launch(void* const* d_in, const int* in_sizes, int n_in,
                              void* d_out, int out_size, void* d_ws, size_t ws_size,
                              hipStream_t stream) {
    const float* h   = (const float*)d_in[0];   // 4096 x 512 fp32
    const int*   adj = (const int*)d_in[1];     // 4096 x 4096 int32
    const float* W   = (const float*)d_in[2];   // 512 x 512 fp32
    const float* a   = (const float*)d_in[3];   // 128 fp32

    char* ws = (char*)d_ws;
    ushort_t* WhT = (ushort_t*)ws;                      // 4 MB
    ushort_t* WT  = (ushort_t*)(ws + (4u << 20));       // 512 KB
    float* expA = (float*)(ws + (4u << 20) + (512u << 10));  // 5 x 128 KB
    float* expC = expA + 8 * 4096;
    float* expT = expC + 8 * 4096;
    float* expB = expT + 8 * 4096;
    float* expD = expB + 8 * 4096;

    transpose_w<<<256, 256, 0, stream>>>(W, WT);
    gemm_whT<<<512, 256, 0, stream>>>(WT, h, a, WhT, expA, expC, expT, expB, expD);
    gat_attn<<<1024, 512, 0, stream>>>(adj, WhT, expA, expC, expT, expB, expD,
                                       (float*)d_out);
}